// Round 17
// baseline (207.670 us; speedup 1.0000x reference)
//
#include <hip/hip_runtime.h>
#include <hip/hip_bf16.h>
#include <hip/hip_cooperative_groups.h>

namespace cg = cooperative_groups;

typedef __attribute__((ext_vector_type(8)))  short s8v;   // 8 bf16
typedef __attribute__((ext_vector_type(4)))  float f4v;   // 16x16 C/D
typedef _Float16 h4 __attribute__((ext_vector_type(4)));  // 4 f16
typedef __attribute__((ext_vector_type(4))) unsigned short u4v;

constexpr int NCn  = 128;
constexpr int DDn  = 65536;
constexpr int XP   = 264;             // padded LDS row (bf16 elems)
constexpr float EPSf = 1.1920929e-07f;

__device__ __forceinline__ float sigm(float x){ return 1.0f/(1.0f + expf(-x)); }
__device__ __forceinline__ float silu_(float x){ return x * sigm(x); }
__device__ __forceinline__ float dsilu_(float x){ float s = sigm(x); return s*(1.0f + x*(1.0f - s)); }

__device__ __forceinline__ unsigned short f2b(float x){
    __hip_bfloat16 b = __float2bfloat16(x);
    unsigned short u; __builtin_memcpy(&u, &b, 2); return u;
}
__device__ __forceinline__ float b2f(unsigned short u){
    __hip_bfloat16 b; __builtin_memcpy(&b, &u, 2); return __bfloat162float(b);
}
__device__ __forceinline__ h4 ldh4(const unsigned short* p){
    h4 r; __builtin_memcpy(&r, p, 8); return r;
}

// fragment-order index: element (row, col) of a [R][256] matrix stored so that
// a wave's MFMA fragment load (tile=row>>4, i=col>>5, lane=(q16,m16), j) is a
// contiguous 1KB read:  addr = ((tile*8 + i)*4 + q16)*128 + m16*8 + j
__device__ __forceinline__ int fidx(int row, int col){
    return (((row >> 4)*8 + (col >> 5))*4 + ((col >> 3) & 3))*128 + (row & 15)*8 + (col & 7);
}

// ---- merged weight prep: z 0..5 tiled transpose fp32->bf16 frag-order,
//      z 6..8 cast-copy frag-order ----
__global__ __launch_bounds__(256) void ktw(const float* __restrict__ Wq,
        const float* __restrict__ Wkv, const float* __restrict__ W0,
        const float* __restrict__ W1, const float* __restrict__ W2,
        const float* __restrict__ W3, unsigned short* __restrict__ WTb,
        unsigned short* __restrict__ WqTb, unsigned short* __restrict__ WkvTb,
        unsigned short* __restrict__ Wb){
    int z = blockIdx.z;
    if (z >= 6){
        const float* S = (z==6)?W1:(z==7)?W2:W3;
        size_t idx = (((size_t)blockIdx.y*8 + blockIdx.x)*256 + threadIdx.x)*2;
        float2 v = *(const float2*)(S + idx);
        ushort2 u; u.x = f2b(v.x); u.y = f2b(v.y);
        int row = (int)(idx >> 8), col = (int)(idx & 255);
        *(ushort2*)(Wb + (size_t)(z-6)*DDn + fidx(row, col)) = u;
        return;
    }
    __shared__ float tl[32][33];
    if (z != 5 && blockIdx.y >= 8) return;
    const float* S; unsigned short* T; int C;
    if (z < 4){ S = (z==0)?W0:(z==1)?W1:(z==2)?W2:W3; T = WTb + (size_t)z*DDn; C = 256; }
    else if (z == 4){ S = Wq; T = WqTb; C = 256; }
    else { S = Wkv; T = WkvTb; C = 512; }
    int k0 = blockIdx.x*32, j0 = blockIdx.y*32;
    int tx = threadIdx.x & 31, ty = threadIdx.x >> 5;
    #pragma unroll
    for (int p = 0; p < 4; ++p)
        tl[ty + 8*p][tx] = S[(size_t)(k0 + ty + 8*p)*C + j0 + tx];
    __syncthreads();
    #pragma unroll
    for (int p = 0; p < 4; ++p){
        int r = j0 + ty + 8*p, k = k0 + tx;   // T[r][k] = S[k][r]
        T[fidx(r, k)] = f2b(tl[tx][ty + 8*p]);
    }
}

// ---- cooperative mega-kernel: phase1 kfb | grid.sync | phase2 kck | grid.sync |
//      phase3 kretr.  128 blocks x 1024 threads, all co-resident. ----
__global__ __launch_bounds__(1024, 1) void kmain(const float* __restrict__ seq,
        const float* __restrict__ wsn, const float* __restrict__ wrn,
        const unsigned short* __restrict__ WkvTb, const unsigned short* __restrict__ WTb,
        const unsigned short* __restrict__ Wb, const unsigned short* __restrict__ WqTb,
        const float* __restrict__ wa, const float* __restrict__ wm,
        const float* __restrict__ wdk,
        float* __restrict__ momg, float* __restrict__ decg,
        unsigned short* __restrict__ XT, unsigned short* __restrict__ GT,
        unsigned short* __restrict__ ucpb,
        const float* __restrict__ wpost, float* __restrict__ out){
    __shared__ unsigned short xs[16][XP];
    __shared__ unsigned short xl[4][16][XP];
    __shared__ unsigned short Gs[16][XP];
    __shared__ float red3[16][4];
    __shared__ unsigned short ts[16][16][18];
    __shared__ unsigned short xc[2][16][XP];
    __shared__ float red[16][16];
    __shared__ float rs[16];

    int tid = threadIdx.x, w = tid >> 6, lane = tid & 63;
    int m16 = lane & 15, q16 = lane >> 4;
    int g = blockIdx.x;
    int n0 = w*16;
    size_t fb = (size_t)w*4096 + q16*128 + m16*8;   // fragment base for rows n0..n0+15

    // ================= phase 1: fwd + bwd dgrads + norm + gates =================
    {
        {   // in-block store-norm: wave w computes row w of sn
            const float4 xv = *(const float4*)(seq + ((size_t)g*16 + w)*256 + lane*4);
            const float4 wv = *(const float4*)(wsn + lane*4);
            float ssq = xv.x*xv.x + xv.y*xv.y + xv.z*xv.z + xv.w*xv.w;
            #pragma unroll
            for (int off = 32; off; off >>= 1) ssq += __shfl_xor(ssq, off, 64);
            float s2 = rsqrtf(ssq*(1.f/256.f) + EPSf);
            u4v sv;
            sv[0] = f2b(xv.x*s2*wv.x); sv[1] = f2b(xv.y*s2*wv.y);
            sv[2] = f2b(xv.z*s2*wv.z); sv[3] = f2b(xv.w*s2*wv.w);
            *(u4v*)(&xs[w][lane*4]) = sv;
        }
        __syncthreads();

        float sc;
        {   // fused gates: one reduction pass, one barrier (reads xs in LDS)
            int d2 = tid & 255, qt = tid >> 8;
            float a = 0.f;
            #pragma unroll
            for (int c = 0; c < 4; ++c)
                a += b2f(xs[qt*4 + c][d2]);
            float cm = a * (1.f/16.f);
            float s0 = cm*wa[d2], s1 = cm*wm[d2], s2 = cm*wdk[d2];
            #pragma unroll
            for (int off = 32; off; off >>= 1){
                s0 += __shfl_down(s0, off, 64);
                s1 += __shfl_down(s1, off, 64);
                s2 += __shfl_down(s2, off, 64);
            }
            if (lane == 0){ red3[w][0] = s0; red3[w][1] = s1; red3[w][2] = s2; }
            __syncthreads();
            float da = 0.f, dm = 0.f, dc = 0.f;
            #pragma unroll
            for (int i = 0; i < 16; ++i){
                da += red3[i][0]; dm += red3[i][1]; dc += red3[i][2];
            }
            sc = -2.f * sigm(da) * (1.f/256.f);
            if (tid == 0){ momg[g] = sigm(dm); decg[g] = sigm(dc); }
        }

        // A-frags from LDS xs
        s8v af[8];
        #pragma unroll
        for (int i = 0; i < 8; ++i) af[i] = *(const s8v*)(&xs[m16][q16*8 + i*32]);

        // prefetch layer-0 weights (used after next barrier)
        s8v bpre[8];
        #pragma unroll
        for (int i = 0; i < 8; ++i) bpre[i] = *(const s8v*)(WTb + fb + i*512);

        f4v vacc;
        {
            f4v ka = {0.f,0.f,0.f,0.f}, va = {0.f,0.f,0.f,0.f};
            const unsigned short* brK = WkvTb + fb;                 // K rows n0..
            const unsigned short* brV = WkvTb + (size_t)DDn + fb;   // V rows 256+n0..
            #pragma unroll
            for (int i = 0; i < 8; ++i){
                s8v bK = *(const s8v*)(brK + i*512);
                s8v bV = *(const s8v*)(brV + i*512);
                ka = __builtin_amdgcn_mfma_f32_16x16x32_bf16(af[i], bK, ka, 0, 0, 0);
                va = __builtin_amdgcn_mfma_f32_16x16x32_bf16(af[i], bV, va, 0, 0, 0);
            }
            vacc = va;
            #pragma unroll
            for (int r = 0; r < 4; ++r) xl[0][4*q16 + r][n0 + m16] = f2b(ka[r]);
        }

        f4v hreg[3];
        #pragma unroll
        for (int l = 0; l < 3; ++l){
            __syncthreads();
            s8v xa[8];
            #pragma unroll
            for (int i = 0; i < 8; ++i)
                xa[i] = *(const s8v*)(&xl[l][m16][q16*8 + i*32]);
            s8v bcur[8];
            #pragma unroll
            for (int i = 0; i < 8; ++i) bcur[i] = bpre[i];
            const unsigned short* nxt = WTb + (size_t)(l+1)*DDn + fb;
            #pragma unroll
            for (int i = 0; i < 8; ++i) bpre[i] = *(const s8v*)(nxt + i*512);
            f4v acc = {0.f,0.f,0.f,0.f};
            #pragma unroll
            for (int i = 0; i < 8; ++i)
                acc = __builtin_amdgcn_mfma_f32_16x16x32_bf16(xa[i], bcur[i], acc, 0, 0, 0);
            hreg[l] = acc;
            #pragma unroll
            for (int r = 0; r < 4; ++r)
                xl[l+1][4*q16 + r][n0 + m16] = f2b(silu_(acc[r]));
        }
        __syncthreads();

        {   // dump XT f16 [l][g][d][c]
            int d = tid & 255, qt = tid >> 8;
            #pragma unroll
            for (int l = 0; l < 4; ++l){
                h4 v;
                #pragma unroll
                for (int j = 0; j < 4; ++j)
                    v[j] = (_Float16)b2f(xl[l][qt*4 + j][d]);
                *(h4*)(XT + (((size_t)l*128 + g)*256 + d)*16 + qt*4) = v;
            }
        }

        {   // layer 3 (pred) -> Gs; prefetch Wb[2] for bwd l=3
            s8v xa[8];
            #pragma unroll
            for (int i = 0; i < 8; ++i)
                xa[i] = *(const s8v*)(&xl[3][m16][q16*8 + i*32]);
            s8v bcur[8];
            #pragma unroll
            for (int i = 0; i < 8; ++i) bcur[i] = bpre[i];
            const unsigned short* nxt = Wb + (size_t)2*DDn + fb;
            #pragma unroll
            for (int i = 0; i < 8; ++i) bpre[i] = *(const s8v*)(nxt + i*512);
            f4v acc = {0.f,0.f,0.f,0.f};
            #pragma unroll
            for (int i = 0; i < 8; ++i)
                acc = __builtin_amdgcn_mfma_f32_16x16x32_bf16(xa[i], bcur[i], acc, 0, 0, 0);
            #pragma unroll
            for (int r = 0; r < 4; ++r)
                Gs[4*q16 + r][n0 + m16] = f2b(sc * (acc[r] - vacc[r]));
        }
        __syncthreads();
        {   // write f16 GT[3][g][d][c]
            int d = tid & 255, qt = tid >> 8;
            h4 v;
            #pragma unroll
            for (int j = 0; j < 4; ++j)
                v[j] = (_Float16)b2f(Gs[qt*4 + j][d]);
            *(h4*)(GT + (((size_t)3*128 + g)*256 + d)*16 + qt*4) = v;
        }

        #pragma unroll
        for (int l = 3; l >= 1; --l){
            s8v gfa[8];
            #pragma unroll
            for (int i = 0; i < 8; ++i)
                gfa[i] = *(const s8v*)(&Gs[m16][q16*8 + i*32]);
            s8v bcur[8];
            #pragma unroll
            for (int i = 0; i < 8; ++i) bcur[i] = bpre[i];
            if (l > 1){
                const unsigned short* nxt = Wb + (size_t)(l-2)*DDn + fb;
                #pragma unroll
                for (int i = 0; i < 8; ++i) bpre[i] = *(const s8v*)(nxt + i*512);
            }
            f4v acc = {0.f,0.f,0.f,0.f};
            #pragma unroll
            for (int i = 0; i < 8; ++i)
                acc = __builtin_amdgcn_mfma_f32_16x16x32_bf16(gfa[i], bcur[i], acc, 0, 0, 0);
            f4v gn;
            #pragma unroll
            for (int r = 0; r < 4; ++r)
                gn[r] = acc[r] * dsilu_(hreg[l-1][r]);
            __syncthreads();
            #pragma unroll
            for (int r = 0; r < 4; ++r)
                Gs[4*q16 + r][n0 + m16] = f2b(gn[r]);
            __syncthreads();
            {
                int d = tid & 255, qt = tid >> 8;
                h4 v;
                #pragma unroll
                for (int j = 0; j < 4; ++j)
                    v[j] = (_Float16)b2f(Gs[qt*4 + j][d]);
                *(h4*)(GT + (((size_t)(l-1)*128 + g)*256 + d)*16 + qt*4) = v;
            }
        }
    }

    cg::this_grid().sync();

    // ================= phase 2: per-chunk U scan, one 16x16 tile per wave ======
    {
        int W = g*16 + w;                   // 0..2047
        int rt = W >> 7, ct = (W >> 3) & 15, bl = W & 7;
        int b = bl >> 2, l = bl & 3;
        int dr = rt*16 + m16;   // G row (dout)
        const unsigned short* Gb = GT + ((size_t)l*128 + b*64)*4096 + (size_t)dr*16 + q16*4;
        const unsigned short* X0 = XT + ((size_t)l*128 + b*64)*4096
                                 + (size_t)(ct*16 + m16)*16 + q16*4;
        int rr = lane & 15, cg2 = lane >> 4;
        int off0;
        {
            int c0 = ct*16 + cg2*4;
            off0 = ((rt*8 + (c0 >> 5))*4 + ((c0 >> 3) & 3))*128 + rr*8 + (c0 & 7);
        }
        f4v us = {0.f,0.f,0.f,0.f}, ms = {0.f,0.f,0.f,0.f};
        #pragma unroll 4
        for (int n = 0; n < 64; ++n){
            float mo = momg[b*64 + n], de = 1.f - decg[b*64 + n];
            h4 a  = ldh4(Gb + (size_t)n*4096);
            h4 x0 = ldh4(X0 + (size_t)n*4096);
            f4v z = {0.f,0.f,0.f,0.f};
            f4v s = __builtin_amdgcn_mfma_f32_16x16x16f16(a, x0, z, 0, 0, 0);
            #pragma unroll
            for (int r = 0; r < 4; ++r){
                float mn = mo*ms[r] + s[r], un = de*us[r] + mn;
                ms[r] = mn; us[r] = un;
                ts[w][4*q16 + r][m16] = f2b(un);
            }
            size_t cb = ((size_t)bl*64 + n)*65536;
            u4v v0;
            #pragma unroll
            for (int j = 0; j < 4; ++j)
                v0[j] = ts[w][rr][cg2*4 + j];
            *(u4v*)(ucpb + cb + off0) = v0;
        }
    }

    cg::this_grid().sync();

    // ================= phase 3: retrieval =====================================
    {
        int b = g >> 6, nl = g & 63;
        const unsigned short* ubase = ucpb + ((size_t)(b*4)*64 + nl)*65536 + fb;

        // prefetch layer-0 U frags (hide under norm + q-proj)
        s8v upre[8];
        #pragma unroll
        for (int i = 0; i < 8; ++i) upre[i] = *(const s8v*)(ubase + i*512);

        {   // in-block retrieve-norm (shifted): wave w computes row w (token p+15)
            int p = nl*16 + w + 15;
            u4v sv = {0,0,0,0};
            if (p < 1024){
                const float4 xv = *(const float4*)(seq + ((size_t)b*1024 + p)*256 + lane*4);
                const float4 wv = *(const float4*)(wrn + lane*4);
                float ssq = xv.x*xv.x + xv.y*xv.y + xv.z*xv.z + xv.w*xv.w;
                #pragma unroll
                for (int off = 32; off; off >>= 1) ssq += __shfl_xor(ssq, off, 64);
                float s2 = rsqrtf(ssq*(1.f/256.f) + EPSf);
                sv[0] = f2b(xv.x*s2*wv.x); sv[1] = f2b(xv.y*s2*wv.y);
                sv[2] = f2b(xv.z*s2*wv.z); sv[3] = f2b(xv.w*s2*wv.w);
            }
            *(u4v*)(&xc[1][w][lane*4]) = sv;
        }
        __syncthreads();

        {   // q-projection (reads rn from xc[1], writes xc[0])
            s8v a[8];
            #pragma unroll
            for (int i = 0; i < 8; ++i) a[i] = *(const s8v*)(&xc[1][m16][q16*8 + i*32]);
            f4v acc = {0.f,0.f,0.f,0.f};
            const unsigned short* br = WqTb + fb;
            #pragma unroll
            for (int i = 0; i < 8; ++i){
                s8v bb = *(const s8v*)(br + i*512);
                acc = __builtin_amdgcn_mfma_f32_16x16x32_bf16(a[i], bb, acc, 0, 0, 0);
            }
            #pragma unroll
            for (int r = 0; r < 4; ++r) xc[0][4*q16 + r][n0 + m16] = f2b(acc[r]);
        }
        __syncthreads();

        f4v hacc;
        for (int l = 0; l < 4; ++l){
            s8v xa[8];
            #pragma unroll
            for (int i = 0; i < 8; ++i)
                xa[i] = *(const s8v*)(&xc[l & 1][m16][q16*8 + i*32]);
            s8v ucur[8];
            #pragma unroll
            for (int i = 0; i < 8; ++i) ucur[i] = upre[i];
            if (l < 3){
                const unsigned short* un = ubase + (size_t)(l+1)*64*65536;
                #pragma unroll
                for (int i = 0; i < 8; ++i) upre[i] = *(const s8v*)(un + i*512);
            }
            const unsigned short* br = WTb + (size_t)l*DDn + fb;
            f4v aW = {0.f,0.f,0.f,0.f}, aU = {0.f,0.f,0.f,0.f};
            #pragma unroll
            for (int i = 0; i < 8; ++i){
                s8v w0 = *(const s8v*)(br + i*512);
                aW = __builtin_amdgcn_mfma_f32_16x16x32_bf16(xa[i], w0, aW, 0, 0, 0);
                aU = __builtin_amdgcn_mfma_f32_16x16x32_bf16(xa[i], ucur[i], aU, 0, 0, 0);
            }
            #pragma unroll
            for (int r = 0; r < 4; ++r) hacc[r] = aW[r] + aU[r];
            if (l < 3){
                #pragma unroll
                for (int r = 0; r < 4; ++r)
                    xc[(l + 1) & 1][4*q16 + r][n0 + m16] = f2b(silu_(hacc[r]));
                __syncthreads();
            }
        }

        // epilogue: post rmsnorm + shift + store
        float part[4];
        #pragma unroll
        for (int r = 0; r < 4; ++r) part[r] = hacc[r]*hacc[r];
        #pragma unroll
        for (int off = 1; off < 16; off <<= 1)
            #pragma unroll
            for (int r = 0; r < 4; ++r) part[r] += __shfl_xor(part[r], off, 64);
        if (m16 == 0)
            #pragma unroll
            for (int r = 0; r < 4; ++r) red[w][4*q16 + r] = part[r];
        __syncthreads();
        if (tid < 16){
            float s = 0.f;
            #pragma unroll
            for (int i = 0; i < 16; ++i) s += red[i][tid];
            rs[tid] = rsqrtf(s*(1.f/256.f) + EPSf);
        }
        __syncthreads();
        {
            int d = n0 + m16;
            float wp = wpost[d];
            #pragma unroll
            for (int r = 0; r < 4; ++r){
                int c = 4*q16 + r;
                int tp = nl*16 + c + 15;
                if (tp < 1024)
                    out[((size_t)b*1024 + tp)*256 + d] = hacc[r]*rs[c]*wp;
            }
        }
        if (nl == 0){
            for (int idx = tid; idx < 15*256; idx += 1024)
                out[(size_t)b*262144 + idx] = 0.f;
        }
    }
}

extern "C" void kernel_launch(void* const* d_in, const int* in_sizes, int n_in,
                              void* d_out, int out_size, void* d_ws, size_t ws_size,
                              hipStream_t stream) {
    const float* seq     = (const float*)d_in[0];
    const float* w_store = (const float*)d_in[1];
    const float* w_retr  = (const float*)d_in[2];
    const float* w_post  = (const float*)d_in[3];
    const float* Wq      = (const float*)d_in[4];
    const float* Wkv     = (const float*)d_in[5];
    const float* w_adapt = (const float*)d_in[6];
    const float* w_mom   = (const float*)d_in[7];
    const float* w_decay = (const float*)d_in[8];
    const float* W0      = (const float*)d_in[9];
    const float* W1      = (const float*)d_in[10];
    const float* W2      = (const float*)d_in[11];
    const float* W3      = (const float*)d_in[12];

    float* momg  = (float*)d_ws;                       // 128
    float* decg  = momg + NCn;                         // 128
    unsigned short* WTb   = (unsigned short*)(decg + NCn + 32);
    unsigned short* Wb    = WTb   + 4*(size_t)DDn;
    unsigned short* WqTb  = Wb    + 3*(size_t)DDn;
    unsigned short* WkvTb = WqTb  + (size_t)DDn;
    unsigned short* XT    = WkvTb + 2*(size_t)DDn;       // f16 [l][g][d][c], 4 MB
    unsigned short* GT    = XT    + (size_t)4*NCn*4096;  // f16 [l][g][d][c], 4 MB
    unsigned short* ucpb  = GT    + (size_t)4*NCn*4096;  // bf16 frag-order U_g, 67 MB
    float* outp = (float*)d_out;

    ktw <<<dim3(8, 16, 9), 256, 0, stream>>>(Wq, Wkv, W0, W1, W2, W3,
                                             WTb, WqTb, WkvTb, Wb);

    void* args[] = { (void*)&seq, (void*)&w_store, (void*)&w_retr,
                     (void*)&WkvTb, (void*)&WTb, (void*)&Wb, (void*)&WqTb,
                     (void*)&w_adapt, (void*)&w_mom, (void*)&w_decay,
                     (void*)&momg, (void*)&decg,
                     (void*)&XT, (void*)&GT, (void*)&ucpb,
                     (void*)&w_post, (void*)&outp };
    hipLaunchCooperativeKernel((void*)kmain, dim3(NCn), dim3(1024),
                               args, 0, stream);
}

// Round 18
// 137.137 us; speedup vs baseline: 1.5143x; 1.5143x over previous
//
#include <hip/hip_runtime.h>
#include <hip/hip_bf16.h>

typedef __attribute__((ext_vector_type(8)))  short s8v;   // 8 bf16
typedef __attribute__((ext_vector_type(4)))  float f4v;   // 16x16 C/D
typedef _Float16 h4 __attribute__((ext_vector_type(4)));  // 4 f16
typedef __attribute__((ext_vector_type(4))) unsigned short u4v;

constexpr int NCn  = 128;
constexpr int DDn  = 65536;
constexpr int XP   = 264;             // padded LDS row (bf16 elems)
constexpr float EPSf = 1.1920929e-07f;

__device__ __forceinline__ float sigm(float x){ return 1.0f/(1.0f + expf(-x)); }
__device__ __forceinline__ float silu_(float x){ return x * sigm(x); }
__device__ __forceinline__ float dsilu_(float x){ float s = sigm(x); return s*(1.0f + x*(1.0f - s)); }

__device__ __forceinline__ unsigned short f2b(float x){
    __hip_bfloat16 b = __float2bfloat16(x);
    unsigned short u; __builtin_memcpy(&u, &b, 2); return u;
}
__device__ __forceinline__ float b2f(unsigned short u){
    __hip_bfloat16 b; __builtin_memcpy(&b, &u, 2); return __bfloat162float(b);
}
__device__ __forceinline__ h4 ldh4(const unsigned short* p){
    h4 r; __builtin_memcpy(&r, p, 8); return r;
}

// fragment-order index: element (row, col) of a [R][256] matrix stored so that
// a wave's MFMA fragment load (tile=row>>4, i=col>>5, lane=(q16,m16), j) is a
// contiguous 1KB read:  addr = ((tile*8 + i)*4 + q16)*128 + m16*8 + j
__device__ __forceinline__ int fidx(int row, int col){
    return (((row >> 4)*8 + (col >> 5))*4 + ((col >> 3) & 3))*128 + (row & 15)*8 + (col & 7);
}

// ---- merged weight prep: z 0..5 tiled transpose fp32->bf16 frag-order,
//      z 6..8 cast-copy frag-order ----
__global__ __launch_bounds__(256) void ktw(const float* __restrict__ Wq,
        const float* __restrict__ Wkv, const float* __restrict__ W0,
        const float* __restrict__ W1, const float* __restrict__ W2,
        const float* __restrict__ W3, unsigned short* __restrict__ WTb,
        unsigned short* __restrict__ WqTb, unsigned short* __restrict__ WkvTb,
        unsigned short* __restrict__ Wb){
    int z = blockIdx.z;
    if (z >= 6){
        const float* S = (z==6)?W1:(z==7)?W2:W3;
        size_t idx = (((size_t)blockIdx.y*8 + blockIdx.x)*256 + threadIdx.x)*2;
        float2 v = *(const float2*)(S + idx);
        ushort2 u; u.x = f2b(v.x); u.y = f2b(v.y);
        int row = (int)(idx >> 8), col = (int)(idx & 255);
        *(ushort2*)(Wb + (size_t)(z-6)*DDn + fidx(row, col)) = u;
        return;
    }
    __shared__ float tl[32][33];
    if (z != 5 && blockIdx.y >= 8) return;
    const float* S; unsigned short* T; int C;
    if (z < 4){ S = (z==0)?W0:(z==1)?W1:(z==2)?W2:W3; T = WTb + (size_t)z*DDn; C = 256; }
    else if (z == 4){ S = Wq; T = WqTb; C = 256; }
    else { S = Wkv; T = WkvTb; C = 512; }
    int k0 = blockIdx.x*32, j0 = blockIdx.y*32;
    int tx = threadIdx.x & 31, ty = threadIdx.x >> 5;
    #pragma unroll
    for (int p = 0; p < 4; ++p)
        tl[ty + 8*p][tx] = S[(size_t)(k0 + ty + 8*p)*C + j0 + tx];
    __syncthreads();
    #pragma unroll
    for (int p = 0; p < 4; ++p){
        int r = j0 + ty + 8*p, k = k0 + tx;   // T[r][k] = S[k][r]
        T[fidx(r, k)] = f2b(tl[tx][ty + 8*p]);
    }
}

// ---- fwd + bwd dgrads + fused norm + fused gates, one block per group, 16 waves ----
// sn computed in-block into LDS xs; writes XT f16 [l][g][d][c], GT f16 [l][g][d][c]
__global__ __launch_bounds__(1024, 1) void kfb(const float* __restrict__ seq,
        const float* __restrict__ wsn,
        const unsigned short* __restrict__ WkvTb, const unsigned short* __restrict__ WTb,
        const unsigned short* __restrict__ Wb,
        const float* __restrict__ wa, const float* __restrict__ wm,
        const float* __restrict__ wdk,
        float* __restrict__ momg, float* __restrict__ decg,
        unsigned short* __restrict__ XT, unsigned short* __restrict__ GT){
    __shared__ unsigned short xs[16][XP];
    __shared__ unsigned short xl[4][16][XP];
    __shared__ unsigned short Gs[16][XP];
    __shared__ float red3[16][4];
    int tid = threadIdx.x, w = tid >> 6, lane = tid & 63;
    int m16 = lane & 15, q16 = lane >> 4;
    int g = blockIdx.x;
    int n0 = w*16;
    size_t fb = (size_t)w*4096 + q16*128 + m16*8;   // fragment base for rows n0..n0+15

    {   // in-block store-norm: wave w computes row w of sn
        const float4 xv = *(const float4*)(seq + ((size_t)g*16 + w)*256 + lane*4);
        const float4 wv = *(const float4*)(wsn + lane*4);
        float ssq = xv.x*xv.x + xv.y*xv.y + xv.z*xv.z + xv.w*xv.w;
        #pragma unroll
        for (int off = 32; off; off >>= 1) ssq += __shfl_xor(ssq, off, 64);
        float s2 = rsqrtf(ssq*(1.f/256.f) + EPSf);
        u4v sv;
        sv[0] = f2b(xv.x*s2*wv.x); sv[1] = f2b(xv.y*s2*wv.y);
        sv[2] = f2b(xv.z*s2*wv.z); sv[3] = f2b(xv.w*s2*wv.w);
        *(u4v*)(&xs[w][lane*4]) = sv;
    }
    __syncthreads();

    float sc;
    {   // fused gates: one reduction pass, one barrier (reads xs in LDS)
        int d2 = tid & 255, qt = tid >> 8;
        float a = 0.f;
        #pragma unroll
        for (int c = 0; c < 4; ++c)
            a += b2f(xs[qt*4 + c][d2]);
        float cm = a * (1.f/16.f);
        float s0 = cm*wa[d2], s1 = cm*wm[d2], s2 = cm*wdk[d2];
        #pragma unroll
        for (int off = 32; off; off >>= 1){
            s0 += __shfl_down(s0, off, 64);
            s1 += __shfl_down(s1, off, 64);
            s2 += __shfl_down(s2, off, 64);
        }
        if (lane == 0){ red3[w][0] = s0; red3[w][1] = s1; red3[w][2] = s2; }
        __syncthreads();
        float da = 0.f, dm = 0.f, dc = 0.f;
        #pragma unroll
        for (int i = 0; i < 16; ++i){
            da += red3[i][0]; dm += red3[i][1]; dc += red3[i][2];
        }
        sc = -2.f * sigm(da) * (1.f/256.f);
        if (tid == 0){ momg[g] = sigm(dm); decg[g] = sigm(dc); }
    }

    // A-frags from LDS xs
    s8v af[8];
    #pragma unroll
    for (int i = 0; i < 8; ++i) af[i] = *(const s8v*)(&xs[m16][q16*8 + i*32]);

    // prefetch layer-0 weights (used after next barrier)
    s8v bpre[8];
    #pragma unroll
    for (int i = 0; i < 8; ++i) bpre[i] = *(const s8v*)(WTb + fb + i*512);

    f4v vacc;
    {
        f4v ka = {0.f,0.f,0.f,0.f}, va = {0.f,0.f,0.f,0.f};
        const unsigned short* brK = WkvTb + fb;                 // K rows n0..
        const unsigned short* brV = WkvTb + (size_t)DDn + fb;   // V rows 256+n0..
        #pragma unroll
        for (int i = 0; i < 8; ++i){
            s8v bK = *(const s8v*)(brK + i*512);
            s8v bV = *(const s8v*)(brV + i*512);
            ka = __builtin_amdgcn_mfma_f32_16x16x32_bf16(af[i], bK, ka, 0, 0, 0);
            va = __builtin_amdgcn_mfma_f32_16x16x32_bf16(af[i], bV, va, 0, 0, 0);
        }
        vacc = va;
        #pragma unroll
        for (int r = 0; r < 4; ++r) xl[0][4*q16 + r][n0 + m16] = f2b(ka[r]);
    }

    f4v hreg[3];
    #pragma unroll
    for (int l = 0; l < 3; ++l){
        __syncthreads();
        s8v xa[8];
        #pragma unroll
        for (int i = 0; i < 8; ++i)
            xa[i] = *(const s8v*)(&xl[l][m16][q16*8 + i*32]);
        s8v bcur[8];
        #pragma unroll
        for (int i = 0; i < 8; ++i) bcur[i] = bpre[i];
        const unsigned short* nxt = WTb + (size_t)(l+1)*DDn + fb;
        #pragma unroll
        for (int i = 0; i < 8; ++i) bpre[i] = *(const s8v*)(nxt + i*512);
        f4v acc = {0.f,0.f,0.f,0.f};
        #pragma unroll
        for (int i = 0; i < 8; ++i)
            acc = __builtin_amdgcn_mfma_f32_16x16x32_bf16(xa[i], bcur[i], acc, 0, 0, 0);
        hreg[l] = acc;
        #pragma unroll
        for (int r = 0; r < 4; ++r)
            xl[l+1][4*q16 + r][n0 + m16] = f2b(silu_(acc[r]));
    }
    __syncthreads();

    {   // dump XT f16 [l][g][d][c]
        int d = tid & 255, qt = tid >> 8;
        #pragma unroll
        for (int l = 0; l < 4; ++l){
            h4 v;
            #pragma unroll
            for (int j = 0; j < 4; ++j)
                v[j] = (_Float16)b2f(xl[l][qt*4 + j][d]);
            *(h4*)(XT + (((size_t)l*128 + g)*256 + d)*16 + qt*4) = v;
        }
    }

    {   // layer 3 (pred) -> Gs; prefetch Wb[2] for bwd l=3
        s8v xa[8];
        #pragma unroll
        for (int i = 0; i < 8; ++i)
            xa[i] = *(const s8v*)(&xl[3][m16][q16*8 + i*32]);
        s8v bcur[8];
        #pragma unroll
        for (int i = 0; i < 8; ++i) bcur[i] = bpre[i];
        const unsigned short* nxt = Wb + (size_t)2*DDn + fb;
        #pragma unroll
        for (int i = 0; i < 8; ++i) bpre[i] = *(const s8v*)(nxt + i*512);
        f4v acc = {0.f,0.f,0.f,0.f};
        #pragma unroll
        for (int i = 0; i < 8; ++i)
            acc = __builtin_amdgcn_mfma_f32_16x16x32_bf16(xa[i], bcur[i], acc, 0, 0, 0);
        #pragma unroll
        for (int r = 0; r < 4; ++r)
            Gs[4*q16 + r][n0 + m16] = f2b(sc * (acc[r] - vacc[r]));
    }
    __syncthreads();
    {   // write f16 GT[3][g][d][c]
        int d = tid & 255, qt = tid >> 8;
        h4 v;
        #pragma unroll
        for (int j = 0; j < 4; ++j)
            v[j] = (_Float16)b2f(Gs[qt*4 + j][d]);
        *(h4*)(GT + (((size_t)3*128 + g)*256 + d)*16 + qt*4) = v;
    }

    #pragma unroll
    for (int l = 3; l >= 1; --l){
        s8v gfa[8];
        #pragma unroll
        for (int i = 0; i < 8; ++i)
            gfa[i] = *(const s8v*)(&Gs[m16][q16*8 + i*32]);
        s8v bcur[8];
        #pragma unroll
        for (int i = 0; i < 8; ++i) bcur[i] = bpre[i];
        if (l > 1){
            const unsigned short* nxt = Wb + (size_t)(l-2)*DDn + fb;
            #pragma unroll
            for (int i = 0; i < 8; ++i) bpre[i] = *(const s8v*)(nxt + i*512);
        }
        f4v acc = {0.f,0.f,0.f,0.f};
        #pragma unroll
        for (int i = 0; i < 8; ++i)
            acc = __builtin_amdgcn_mfma_f32_16x16x32_bf16(gfa[i], bcur[i], acc, 0, 0, 0);
        f4v gn;
        #pragma unroll
        for (int r = 0; r < 4; ++r)
            gn[r] = acc[r] * dsilu_(hreg[l-1][r]);
        __syncthreads();
        #pragma unroll
        for (int r = 0; r < 4; ++r)
            Gs[4*q16 + r][n0 + m16] = f2b(gn[r]);
        __syncthreads();
        {
            int d = tid & 255, qt = tid >> 8;
            h4 v;
            #pragma unroll
            for (int j = 0; j < 4; ++j)
                v[j] = (_Float16)b2f(Gs[qt*4 + j][d]);
            *(h4*)(GT + (((size_t)(l-1)*128 + g)*256 + d)*16 + qt*4) = v;
        }
    }
}

// ---- per-chunk update scan -> bf16 U_g checkpoints (frag-order) ----
// grid (16 rt, 16 ct, 8 bl), 1 wave/block (2048 waves = 2/SIMD);
// in-wave LDS transpose -> each lane stores 8B contiguous (coalesced 2x256B)
__global__ __launch_bounds__(64, 1) void kck(const unsigned short* __restrict__ XT,
        const unsigned short* __restrict__ GT, const float* __restrict__ momg,
        const float* __restrict__ decg, unsigned short* __restrict__ ucpb){
    __shared__ unsigned short ts[16][18];
    int lane = threadIdx.x;
    int m16 = lane & 15, q16 = lane >> 4;
    int rt = blockIdx.x, ct = blockIdx.y, bl = blockIdx.z;
    int b = bl >> 2, l = bl & 3;
    int dr = rt*16 + m16;   // G row (dout)
    const unsigned short* Gb = GT + ((size_t)l*128 + b*64)*4096 + (size_t)dr*16 + q16*4;
    const unsigned short* X0 = XT + ((size_t)l*128 + b*64)*4096
                             + (size_t)(ct*16 + m16)*16 + q16*4;
    // transposed-store lane mapping: row rr, col group cg*4
    int rr = lane & 15, cg = lane >> 4;
    int off0;
    {
        int c0 = ct*16 + cg*4;
        off0 = ((rt*8 + (c0 >> 5))*4 + ((c0 >> 3) & 3))*128 + rr*8 + (c0 & 7);
    }
    f4v us = {0.f,0.f,0.f,0.f}, ms = {0.f,0.f,0.f,0.f};
    #pragma unroll 4
    for (int n = 0; n < 64; ++n){
        float mo = momg[b*64 + n], de = 1.f - decg[b*64 + n];
        h4 a  = ldh4(Gb + (size_t)n*4096);
        h4 x0 = ldh4(X0 + (size_t)n*4096);
        f4v z = {0.f,0.f,0.f,0.f};
        f4v s = __builtin_amdgcn_mfma_f32_16x16x16f16(a, x0, z, 0, 0, 0);
        #pragma unroll
        for (int r = 0; r < 4; ++r){
            float mn = mo*ms[r] + s[r], un = de*us[r] + mn;
            ms[r] = mn; us[r] = un;
            ts[4*q16 + r][m16] = f2b(un);
        }
        // in-wave transpose read (compiler inserts lgkmcnt) + coalesced 8B stores
        size_t cb = ((size_t)bl*64 + n)*65536;
        u4v v0;
        #pragma unroll
        for (int j = 0; j < 4; ++j)
            v0[j] = ts[rr][cg*4 + j];
        *(u4v*)(ucpb + cb + off0) = v0;
    }
}

// ---- retrieval: fused retrieve-norm + q-proj + 4 layers { x @ (W_l + U_g) } ----
// 16 waves; frag loads contiguous 1KB/wave; U prefetched one layer ahead
__global__ __launch_bounds__(1024, 1) void kretr(const float* __restrict__ seq,
        const float* __restrict__ wrn,
        const unsigned short* __restrict__ WqTb, const unsigned short* __restrict__ WTb,
        const unsigned short* __restrict__ ucpb, const float* __restrict__ wpost,
        float* __restrict__ out){
    __shared__ unsigned short xc[2][16][XP];
    __shared__ float red[16][16];
    __shared__ float rs[16];
    int tid = threadIdx.x, w = tid >> 6, lane = tid & 63;
    int m16 = lane & 15, q16 = lane >> 4;
    int g = blockIdx.x;
    int b = g >> 6, nl = g & 63;
    int n0 = w*16;
    size_t fb = (size_t)w*4096 + q16*128 + m16*8;   // fragment base (rows n0..n0+15)
    const unsigned short* ubase = ucpb + ((size_t)(b*4)*64 + nl)*65536 + fb;

    // prefetch layer-0 U frags (hide under norm + q-proj)
    s8v upre[8];
    #pragma unroll
    for (int i = 0; i < 8; ++i) upre[i] = *(const s8v*)(ubase + i*512);

    {   // in-block retrieve-norm (shifted): wave w computes row w (token p+15)
        int p = nl*16 + w + 15;
        u4v sv = {0,0,0,0};
        if (p < 1024){
            const float4 xv = *(const float4*)(seq + ((size_t)b*1024 + p)*256 + lane*4);
            const float4 wv = *(const float4*)(wrn + lane*4);
            float ssq = xv.x*xv.x + xv.y*xv.y + xv.z*xv.z + xv.w*xv.w;
            #pragma unroll
            for (int off = 32; off; off >>= 1) ssq += __shfl_xor(ssq, off, 64);
            float s2 = rsqrtf(ssq*(1.f/256.f) + EPSf);
            sv[0] = f2b(xv.x*s2*wv.x); sv[1] = f2b(xv.y*s2*wv.y);
            sv[2] = f2b(xv.z*s2*wv.z); sv[3] = f2b(xv.w*s2*wv.w);
        }
        *(u4v*)(&xc[1][w][lane*4]) = sv;
    }
    __syncthreads();

    {   // q-projection (reads rn from xc[1], writes xc[0])
        s8v a[8];
        #pragma unroll
        for (int i = 0; i < 8; ++i) a[i] = *(const s8v*)(&xc[1][m16][q16*8 + i*32]);
        f4v acc = {0.f,0.f,0.f,0.f};
        const unsigned short* br = WqTb + fb;
        #pragma unroll
        for (int i = 0; i < 8; ++i){
            s8v bb = *(const s8v*)(br + i*512);
            acc = __builtin_amdgcn_mfma_f32_16x16x32_bf16(a[i], bb, acc, 0, 0, 0);
        }
        #pragma unroll
        for (int r = 0; r < 4; ++r) xc[0][4*q16 + r][n0 + m16] = f2b(acc[r]);
    }
    __syncthreads();

    f4v hacc;
    for (int l = 0; l < 4; ++l){
        s8v xa[8];
        #pragma unroll
        for (int i = 0; i < 8; ++i)
            xa[i] = *(const s8v*)(&xc[l & 1][m16][q16*8 + i*32]);
        s8v ucur[8];
        #pragma unroll
        for (int i = 0; i < 8; ++i) ucur[i] = upre[i];
        if (l < 3){
            const unsigned short* un = ubase + (size_t)(l+1)*64*65536;
            #pragma unroll
            for (int i = 0; i < 8; ++i) upre[i] = *(const s8v*)(un + i*512);
        }
        const unsigned short* br = WTb + (size_t)l*DDn + fb;
        f4v aW = {0.f,0.f,0.f,0.f}, aU = {0.f,0.f,0.f,0.f};
        #pragma unroll
        for (int i = 0; i < 8; ++i){
            s8v w0 = *(const s8v*)(br + i*512);
            aW = __builtin_amdgcn_mfma_f32_16x16x32_bf16(xa[i], w0, aW, 0, 0, 0);
            aU = __builtin_amdgcn_mfma_f32_16x16x32_bf16(xa[i], ucur[i], aU, 0, 0, 0);
        }
        #pragma unroll
        for (int r = 0; r < 4; ++r) hacc[r] = aW[r] + aU[r];
        if (l < 3){
            #pragma unroll
            for (int r = 0; r < 4; ++r)
                xc[(l + 1) & 1][4*q16 + r][n0 + m16] = f2b(silu_(hacc[r]));
            __syncthreads();
        }
    }

    // epilogue: post rmsnorm + shift + store
    float part[4];
    #pragma unroll
    for (int r = 0; r < 4; ++r) part[r] = hacc[r]*hacc[r];
    #pragma unroll
    for (int off = 1; off < 16; off <<= 1)
        #pragma unroll
        for (int r = 0; r < 4; ++r) part[r] += __shfl_xor(part[r], off, 64);
    if (m16 == 0)
        #pragma unroll
        for (int r = 0; r < 4; ++r) red[w][4*q16 + r] = part[r];
    __syncthreads();
    if (tid < 16){
        float s = 0.f;
        #pragma unroll
        for (int i = 0; i < 16; ++i) s += red[i][tid];
        rs[tid] = rsqrtf(s*(1.f/256.f) + EPSf);
    }
    __syncthreads();
    {
        int d = n0 + m16;
        float wp = wpost[d];
        #pragma unroll
        for (int r = 0; r < 4; ++r){
            int c = 4*q16 + r;
            int tp = nl*16 + c + 15;
            if (tp < 1024)
                out[((size_t)b*1024 + tp)*256 + d] = hacc[r]*rs[c]*wp;
        }
    }
    if (nl == 0){
        for (int idx = tid; idx < 15*256; idx += 1024)
            out[(size_t)b*262144 + idx] = 0.f;
    }
}

extern "C" void kernel_launch(void* const* d_in, const int* in_sizes, int n_in,
                              void* d_out, int out_size, void* d_ws, size_t ws_size,
                              hipStream_t stream) {
    const float* seq     = (const float*)d_in[0];
    const float* w_store = (const float*)d_in[1];
    const float* w_retr  = (const float*)d_in[2];
    const float* w_post  = (const float*)d_in[3];
    const float* Wq      = (const float*)d_in[4];
    const float* Wkv     = (const float*)d_in[5];
    const float* w_adapt = (const float*)d_in[6];
    const float* w_mom   = (const float*)d_in[7];
    const float* w_decay = (const float*)d_in[8];
    const float* W0      = (const float*)d_in[9];
    const float* W1      = (const float*)d_in[10];
    const float* W2      = (const float*)d_in[11];
    const float* W3      = (const float*)d_in[12];

    float* momg  = (float*)d_ws;                       // 128
    float* decg  = momg + NCn;                         // 128
    unsigned short* WTb   = (unsigned short*)(decg + NCn + 32);
    unsigned short* Wb    = WTb   + 4*(size_t)DDn;
    unsigned short* WqTb  = Wb    + 3*(size_t)DDn;
    unsigned short* WkvTb = WqTb  + (size_t)DDn;
    unsigned short* XT    = WkvTb + 2*(size_t)DDn;       // f16 [l][g][d][c], 4 MB
    unsigned short* GT    = XT    + (size_t)4*NCn*4096;  // f16 [l][g][d][c], 4 MB
    unsigned short* ucpb  = GT    + (size_t)4*NCn*4096;  // bf16 frag-order U_g, 67 MB

    ktw   <<<dim3(8, 16, 9),  256,  0, stream>>>(Wq, Wkv, W0, W1, W2, W3,
                                                 WTb, WqTb, WkvTb, Wb);
    kfb   <<<dim3(NCn),       1024, 0, stream>>>(seq, w_store, WkvTb, WTb, Wb,
                                                 w_adapt, w_mom, w_decay,
                                                 momg, decg, XT, GT);
    kck   <<<dim3(16, 16, 8), 64,   0, stream>>>(XT, GT, momg, decg, ucpb);
    kretr <<<dim3(NCn),       1024, 0, stream>>>(seq, w_retr, WqTb, WTb, ucpb,
                                                 w_post, (float*)d_out);
}